// Round 5
// baseline (234.806 us; speedup 1.0000x reference)
//
#include <hip/hip_runtime.h>
#include <hip/hip_bf16.h>
#include <math.h>

#define HID 1024
#define INTER 8192
#define TT 4096  // tokens = B*S

typedef __bf16 bf16x8 __attribute__((ext_vector_type(8)));
typedef float f32x4 __attribute__((ext_vector_type(4)));

__device__ __forceinline__ void gll16(const void* g, void* l) {
    __builtin_amdgcn_global_load_lds(
        (const __attribute__((address_space(1))) void*)g,
        (__attribute__((address_space(3))) void*)l, 16, 0, 0);
}

// ---------------------------------------------------------------------------
// merged prep: role 0 (blocks 0..1023): cast x->bf16 + s[t]=ew0+ew1
//              role 1 (blocks 1024..9215): transpose-cast w1 [1024][8192] -> w1t
//              role 2 (blocks 9216..17407): transpose-cast w2 [8192][1024] -> w2t
// ---------------------------------------------------------------------------
__device__ __forceinline__ void tcast_tile(const float* __restrict__ in,
                                           __hip_bfloat16* __restrict__ out,
                                           int R, int C, int bx, int by, int tid) {
    __shared__ float tile[32][33];
    const int tx = tid & 31, ty = tid >> 5;  // 32x8
    const int br = by * 32, bc = bx * 32;
#pragma unroll
    for (int j = 0; j < 32; j += 8)
        tile[ty + j][tx] = in[(size_t)(br + ty + j) * C + bc + tx];
    __syncthreads();
#pragma unroll
    for (int j = 0; j < 32; j += 8)
        out[(size_t)(bc + ty + j) * R + br + tx] = __float2bfloat16(tile[tx][ty + j]);
}

__global__ void k_prep(const float* __restrict__ x, const float* __restrict__ ew,
                       const float* __restrict__ w1, const float* __restrict__ w2,
                       __hip_bfloat16* __restrict__ xb, float* __restrict__ s,
                       __hip_bfloat16* __restrict__ w1t, __hip_bfloat16* __restrict__ w2t) {
    const int bid = blockIdx.x, tid = threadIdx.x;
    if (bid < 1024) {
        const int n4 = (TT * HID) / 4;
        const int stride = 1024 * 256;
        for (int i = bid * 256 + tid; i < n4; i += stride) {
            float4 v = ((const float4*)x)[i];
            __hip_bfloat16* o = xb + (size_t)i * 4;
            o[0] = __float2bfloat16(v.x);
            o[1] = __float2bfloat16(v.y);
            o[2] = __float2bfloat16(v.z);
            o[3] = __float2bfloat16(v.w);
        }
        for (int t = bid * 256 + tid; t < TT; t += stride)
            s[t] = ew[2 * t] + ew[2 * t + 1];
    } else if (bid < 1024 + 8192) {
        const int b = bid - 1024;  // w1: R=1024, C=8192 -> bx in [0,256), by in [0,32)
        tcast_tile(w1, w1t, HID, INTER, b % 256, b / 256, tid);
    } else {
        const int b = bid - (1024 + 8192);  // w2: R=8192, C=1024 -> bx in [0,32), by in [0,256)
        tcast_tile(w2, w2t, INTER, HID, b % 32, b / 32, tid);
    }
}

// ---------------------------------------------------------------------------
// 256x256 tile (x CSEG sequential column tiles per block), BK=64, 8 waves
// (2Mx4N), 8-phase schedule, counted vmcnt, XOR swizzle (granule ^= row&7) on
// global source + LDS read (rule #21). Waits are __builtin_amdgcn_s_waitcnt
// intrinsics (no inline-asm memory clobbers); sched_barrier(0) pins.
// EPI=0: gelu -> bf16 hOut.   EPI=1: unsafeAtomicAdd(s[row]*acc) into f32 fOut.
// ---------------------------------------------------------------------------
template <int EPI, int CSEG>
__global__ __launch_bounds__(512, 2) void k_gemm8(
    const __hip_bfloat16* __restrict__ A, const __hip_bfloat16* __restrict__ Bt,
    __hip_bfloat16* __restrict__ hOut, float* __restrict__ fOut,
    const float* __restrict__ s, int Kfull, int nt, int Nout) {
    __shared__ __hip_bfloat16 sA[2][2][128][64];  // [buf][half][row][k]
    __shared__ __hip_bfloat16 sB[2][2][128][64];
    const int tid = threadIdx.x;
    const int lane = tid & 63, wid = tid >> 6;
    const int wr = wid >> 2, wc = wid & 3;  // 2x4 wave grid; wave tile 128x64

    // XCD-bijective swizzle over flattened (y,x); nwg % 8 == 0 by construction.
    const int nwg = gridDim.x * gridDim.y;
    const int wg = blockIdx.y * gridDim.x + blockIdx.x;
    const int swz = (wg & 7) * (nwg >> 3) + (wg >> 3);
    const int brow = (swz / gridDim.x) * 256;
    const int bcol0 = (swz % gridDim.x) * (256 * CSEG);
    const size_t kbase = (size_t)blockIdx.z * ((size_t)nt * 64);

    // staging: thread t loads 16B granule (t&7), row (t>>3) (+64 on 2nd gll16);
    // global col pre-swizzled so linear LDS dest + swizzled read match (#21).
    const int rstage = tid >> 3;
    const int colsw = (((tid & 7) ^ (rstage & 7)) << 3);  // elements
    const __hip_bfloat16* gA = A + (size_t)(brow + rstage) * Kfull + kbase + colsw;
    const __hip_bfloat16* gB0 = Bt + (size_t)(bcol0 + rstage) * Kfull + kbase + colsw;
    const size_t rowStep = (size_t)64 * Kfull;
    const size_t halfStep = (size_t)128 * Kfull;

    char* ldsA0 = (char*)&sA[0][0][0][0] + wid * 1024;
    char* ldsB0 = (char*)&sB[0][0][0][0] + wid * 1024;

    // read-side swizzled granule byte offsets for ks=0,1
    const int g0 = (((lane >> 4)) ^ (lane & 7)) << 4;
    const int g1 = ((4 + (lane >> 4)) ^ (lane & 7)) << 4;
    const char* rdA = (const char*)&sA[0][wr][0][0] + (lane & 15) * 128;
    const char* rdB = (const char*)&sB[0][wc >> 1][0][0] + (wc & 1) * 8192 + (lane & 15) * 128;

#define STAGE_A(buf, half, t)                                              \
    do {                                                                   \
        const __hip_bfloat16* _g = gA + (half) * halfStep + (size_t)(t) * 64; \
        char* _l = ldsA0 + (buf) * 32768 + (half) * 16384;                 \
        gll16(_g, _l);                                                     \
        gll16(_g + rowStep, _l + 8192);                                    \
    } while (0)
#define STAGE_B(buf, half, t)                                              \
    do {                                                                   \
        const __hip_bfloat16* _g = gBc + (half) * halfStep + (size_t)(t) * 64; \
        char* _l = ldsB0 + (buf) * 32768 + (half) * 16384;                 \
        gll16(_g, _l);                                                     \
        gll16(_g + rowStep, _l + 8192);                                    \
    } while (0)
#define PIN() __builtin_amdgcn_sched_barrier(0)
#define BAR()                              \
    do {                                   \
        PIN();                             \
        __builtin_amdgcn_s_barrier();      \
        PIN();                             \
    } while (0)
#define WAIT_LGKM0() __builtin_amdgcn_s_waitcnt(0xC07F)  // lgkmcnt(0)
#define WAIT_LGKM8() __builtin_amdgcn_s_waitcnt(0xC87F)  // lgkmcnt(8)
#define WAIT_VM4() __builtin_amdgcn_s_waitcnt(0x0F74)    // vmcnt(4)
#define WAIT_VM0() __builtin_amdgcn_s_waitcnt(0x0F70)    // vmcnt(0)
#define RD(base, buf, r2048, ks) \
    (*(const bf16x8*)((base) + (buf) * 32768 + (r2048) * 2048 + ((ks) ? g1 : g0)))
#define MM_Q(mbase, nbase, bfr)                                                   \
    _Pragma("unroll") for (int ks = 0; ks < 2; ++ks)                              \
    _Pragma("unroll") for (int m = 0; m < 4; ++m)                                 \
    _Pragma("unroll") for (int n = 0; n < 2; ++n)                                 \
        acc[(mbase) + m][(nbase) + n] = __builtin_amdgcn_mfma_f32_16x16x32_bf16(  \
            aF[m][ks], bfr[n][ks], acc[(mbase) + m][(nbase) + n], 0, 0, 0);
#define MFMA_PHASE(mbase, nbase, bfr)     \
    do {                                  \
        WAIT_LGKM0();                     \
        PIN();                            \
        __builtin_amdgcn_s_setprio(1);    \
        MM_Q(mbase, nbase, bfr);          \
        __builtin_amdgcn_s_setprio(0);    \
        PIN();                            \
    } while (0)

#pragma unroll 1
    for (int cs = 0; cs < CSEG; ++cs) {
        const __hip_bfloat16* gBc = gB0 + (size_t)cs * 256 * Kfull;
        const int bcol = bcol0 + cs * 256;

        f32x4 acc[8][4] = {};
        bf16x8 aF[4][2], b01[2][2], b23[2][2];

        // prologue: tile0 (all 4 halves, buf0) + tile1 B-halves (buf1).
        STAGE_B(0, 0, 0);
        STAGE_B(0, 1, 0);
        STAGE_A(0, 0, 0);
        STAGE_A(0, 1, 0);
        STAGE_B(1, 0, 1);
        STAGE_B(1, 1, 1);
        WAIT_VM4();
        BAR();

        const int iters = nt >> 1;
        for (int i = 0; i < iters; ++i) {
            const bool full = (i + 1 < iters);
            const int t1 = 2 * i + 1, t2 = 2 * i + 2, t3 = 2 * i + 3;

            // phase 1: tile 2i (buf0): read A[m0-3]+B[n0-1]; MFMA m0-3 x n0-1
#pragma unroll
            for (int m = 0; m < 4; ++m) {
                aF[m][0] = RD(rdA, 0, m, 0);
                aF[m][1] = RD(rdA, 0, m, 1);
            }
#pragma unroll
            for (int n = 0; n < 2; ++n) {
                b01[n][0] = RD(rdB, 0, n, 0);
                b01[n][1] = RD(rdB, 0, n, 1);
            }
            STAGE_A(1, 0, t1);
            WAIT_LGKM8();
            BAR();
            MFMA_PHASE(0, 0, b01);
            BAR();

            // phase 2: read B[n2-3]; MFMA m0-3 x n2-3
#pragma unroll
            for (int n = 0; n < 2; ++n) {
                b23[n][0] = RD(rdB, 0, 2 + n, 0);
                b23[n][1] = RD(rdB, 0, 2 + n, 1);
            }
            STAGE_A(1, 1, t1);
            BAR();
            MFMA_PHASE(0, 2, b23);
            BAR();

            // phase 3: read A[m4-7]; MFMA m4-7 x n2-3
#pragma unroll
            for (int m = 0; m < 4; ++m) {
                aF[m][0] = RD(rdA, 0, 4 + m, 0);
                aF[m][1] = RD(rdA, 0, 4 + m, 1);
            }
            if (full) STAGE_B(0, 0, t2);
            BAR();
            MFMA_PHASE(4, 2, b23);
            BAR();

            // phase 4: no ds_read; MFMA m4-7 x n0-1 (b01 kept in regs)
            if (full) STAGE_B(0, 1, t2);
            BAR();
            MFMA_PHASE(4, 0, b01);
            if (full)
                WAIT_VM4();
            else
                WAIT_VM0();
            BAR();

            // phase 5: tile 2i+1 (buf1): read A[m0-3]+B[n0-1]
#pragma unroll
            for (int m = 0; m < 4; ++m) {
                aF[m][0] = RD(rdA, 1, m, 0);
                aF[m][1] = RD(rdA, 1, m, 1);
            }
#pragma unroll
            for (int n = 0; n < 2; ++n) {
                b01[n][0] = RD(rdB, 1, n, 0);
                b01[n][1] = RD(rdB, 1, n, 1);
            }
            if (full) STAGE_A(0, 0, t2);
            WAIT_LGKM8();
            BAR();
            MFMA_PHASE(0, 0, b01);
            BAR();

            // phase 6: read B[n2-3]
#pragma unroll
            for (int n = 0; n < 2; ++n) {
                b23[n][0] = RD(rdB, 1, 2 + n, 0);
                b23[n][1] = RD(rdB, 1, 2 + n, 1);
            }
            if (full) STAGE_A(0, 1, t2);
            BAR();
            MFMA_PHASE(0, 2, b23);
            BAR();

            // phase 7: read A[m4-7]
#pragma unroll
            for (int m = 0; m < 4; ++m) {
                aF[m][0] = RD(rdA, 1, 4 + m, 0);
                aF[m][1] = RD(rdA, 1, 4 + m, 1);
            }
            if (full) STAGE_B(1, 0, t3);
            BAR();
            MFMA_PHASE(4, 2, b23);
            BAR();

            // phase 8: MFMA m4-7 x n0-1
            if (full) STAGE_B(1, 1, t3);
            BAR();
            MFMA_PHASE(4, 0, b01);
            if (full)
                WAIT_VM4();
            else
                WAIT_VM0();
            BAR();
        }

        // epilogue (stores are vmcnt-FIFO ordered ahead of next segment's DMA,
        // so the next prologue's WAIT_VM4 remains correct)
        const int orow = brow + wr * 128 + ((lane >> 4) << 2);
        const int ocol = bcol + wc * 64 + (lane & 15);
#pragma unroll
        for (int m = 0; m < 8; ++m) {
#pragma unroll
            for (int j = 0; j < 4; ++j) {
                const int r = orow + m * 16 + j;
                const size_t ro = (size_t)r * Nout;
                if (EPI == 0) {
#pragma unroll
                    for (int n = 0; n < 4; ++n) {
                        float v = acc[m][n][j];
                        float u = 1.5957691216057308f * (v + 0.044715f * v * v * v);
                        float g = v / (1.0f + __expf(-u));
                        hOut[ro + ocol + n * 16] = __float2bfloat16(g);
                    }
                } else {
                    const float sc = s[r];
#pragma unroll
                    for (int n = 0; n < 4; ++n)
                        unsafeAtomicAdd(&fOut[ro + ocol + n * 16], sc * acc[m][n][j]);
                }
            }
        }
    }
#undef STAGE_A
#undef STAGE_B
#undef PIN
#undef BAR
#undef WAIT_LGKM0
#undef WAIT_LGKM8
#undef WAIT_VM4
#undef WAIT_VM0
#undef RD
#undef MM_Q
#undef MFMA_PHASE
}

extern "C" void kernel_launch(void* const* d_in, const int* in_sizes, int n_in,
                              void* d_out, int out_size, void* d_ws, size_t ws_size,
                              hipStream_t stream) {
    const float* x = (const float*)d_in[0];
    // d_in[1] = scores (unused), d_in[3] = top_experts (unused)
    const float* ew = (const float*)d_in[2];
    const float* w1 = (const float*)d_in[4];
    const float* w2 = (const float*)d_in[5];
    float* out = (float*)d_out;

    char* ws = (char*)d_ws;
    float* s = (float*)ws;                                                    // 16 KB
    __hip_bfloat16* xb = (__hip_bfloat16*)(ws + 16384);                       // 8 MB
    __hip_bfloat16* w1t = (__hip_bfloat16*)(ws + 16384 + 8388608);            // 16 MB
    __hip_bfloat16* w2t = (__hip_bfloat16*)(ws + 16384 + 8388608 + 16777216); // 16 MB
    __hip_bfloat16* h = (__hip_bfloat16*)(ws + 16384 + 8388608 + 2 * 16777216); // 64 MB

    // merged prep: cast+scale (1024 blocks) + w1 transpose (8192) + w2 transpose (8192)
    k_prep<<<1024 + 8192 + 8192, 256, 0, stream>>>(x, ew, w1, w2, xb, s, w1t, w2t);

    // GEMM1: [4096 x 1024] x [1024 x 8192] -> h (gelu, bf16); 256x512 per block
    dim3 g1(INTER / 512, TT / 256, 1);  // 16 x 16 = 256 blocks, 1/CU, 16 iters
    k_gemm8<0, 2><<<g1, 512, 0, stream>>>(xb, w1t, h, nullptr, nullptr, HID, HID / 64, INTER);

    // GEMM2: [4096 x 8192] x [8192 x 1024] -> out (f32, split-K=4 atomic combine)
    hipMemsetAsync(out, 0, (size_t)TT * HID * sizeof(float), stream);
    dim3 g2(HID / 256, TT / 256, 4);  // 4 x 16 x 4 = 256 blocks
    k_gemm8<1, 1><<<g2, 512, 0, stream>>>(h, w2t, nullptr, out, s, INTER, 2048 / 64, HID);
}

// Round 6
// 210.851 us; speedup vs baseline: 1.1136x; 1.1136x over previous
//
#include <hip/hip_runtime.h>
#include <hip/hip_bf16.h>
#include <math.h>

#define HID 1024
#define INTER 8192
#define TT 4096  // tokens = B*S

typedef __bf16 bf16x8 __attribute__((ext_vector_type(8)));
typedef float f32x4 __attribute__((ext_vector_type(4)));

__device__ __forceinline__ void gll16(const void* g, void* l) {
    __builtin_amdgcn_global_load_lds(
        (const __attribute__((address_space(1))) void*)g,
        (__attribute__((address_space(3))) void*)l, 16, 0, 0);
}

// inline-asm LDS read: invisible to SIInsertWaitcnts, so the compiler cannot
// insert conservative vmcnt drains ordering it against in-flight
// global_load_lds. RAW ordering is ours: counted vmcnt + lgkmcnt(0) + PIN.
__device__ __forceinline__ bf16x8 ds_read128(unsigned addr) {
    bf16x8 r;
    asm volatile("ds_read_b128 %0, %1" : "=v"(r) : "v"(addr));
    return r;
}

// cast x -> bf16, compute per-token scale s[t] = ew[t,0]+ew[t,1]
__global__ void k_prep(const float* __restrict__ x, const float* __restrict__ ew,
                       __hip_bfloat16* __restrict__ xb, float* __restrict__ s,
                       int n4, int T) {
    int stride = gridDim.x * blockDim.x;
    for (int i = blockIdx.x * blockDim.x + threadIdx.x; i < n4; i += stride) {
        float4 v = ((const float4*)x)[i];
        __hip_bfloat16* o = xb + (size_t)i * 4;
        o[0] = __float2bfloat16(v.x);
        o[1] = __float2bfloat16(v.y);
        o[2] = __float2bfloat16(v.z);
        o[3] = __float2bfloat16(v.w);
    }
    for (int t = blockIdx.x * blockDim.x + threadIdx.x; t < T; t += stride)
        s[t] = ew[2 * t] + ew[2 * t + 1];
}

// transpose + cast: in f32 [R][C] -> out bf16 [C][R]
__global__ void k_tcast(const float* __restrict__ in, __hip_bfloat16* __restrict__ out,
                        int R, int C) {
    __shared__ float tile[32][33];
    const int tx = threadIdx.x & 31, ty = threadIdx.x >> 5;  // 32x8
    const int br = blockIdx.y * 32, bc = blockIdx.x * 32;
#pragma unroll
    for (int j = 0; j < 32; j += 8)
        tile[ty + j][tx] = in[(size_t)(br + ty + j) * C + bc + tx];
    __syncthreads();
#pragma unroll
    for (int j = 0; j < 32; j += 8)
        out[(size_t)(bc + ty + j) * R + br + tx] = __float2bfloat16(tile[tx][ty + j]);
}

// ---------------------------------------------------------------------------
// 256x256 tile, BK=64, 8 waves (2Mx4N), 8-phase schedule, counted vmcnt,
// XOR swizzle (granule ^= row&7) on global source + LDS read (rule #21).
// Fragment loads are inline-asm ds_read_b128 (no memory clobber) so the
// waitcnt pass cannot serialize them against the global_load_lds pipeline.
// EPI=0: gelu -> bf16 hOut.   EPI=1: unsafeAtomicAdd(s[row]*acc) into f32 fOut.
// ---------------------------------------------------------------------------
template <int EPI>
__global__ __launch_bounds__(512, 2) void k_gemm8(
    const __hip_bfloat16* __restrict__ A, const __hip_bfloat16* __restrict__ Bt,
    __hip_bfloat16* __restrict__ hOut, float* __restrict__ fOut,
    const float* __restrict__ s, int Kfull, int nt, int Nout) {
    __shared__ __hip_bfloat16 sA[2][2][128][64];  // [buf][half][row][k]
    __shared__ __hip_bfloat16 sB[2][2][128][64];
    const int tid = threadIdx.x;
    const int lane = tid & 63, wid = tid >> 6;
    const int wr = wid >> 2, wc = wid & 3;  // 2x4 wave grid; wave tile 128x64

    // XCD-bijective swizzle over flattened (y,x); nwg % 8 == 0 by construction.
    const int nwg = gridDim.x * gridDim.y;
    const int wg = blockIdx.y * gridDim.x + blockIdx.x;
    const int swz = (wg & 7) * (nwg >> 3) + (wg >> 3);
    const int brow = (swz / gridDim.x) * 256;
    const int bcol = (swz % gridDim.x) * 256;
    const size_t kbase = (size_t)blockIdx.z * ((size_t)nt * 64);

    // staging: thread t loads 16B granule (t&7), row (t>>3) (+64 on 2nd gll16);
    // global col pre-swizzled so linear LDS dest + swizzled read match (#21).
    const int rstage = tid >> 3;
    const int colsw = (((tid & 7) ^ (rstage & 7)) << 3);  // elements
    const __hip_bfloat16* gA = A + (size_t)(brow + rstage) * Kfull + kbase + colsw;
    const __hip_bfloat16* gB = Bt + (size_t)(bcol + rstage) * Kfull + kbase + colsw;
    const size_t rowStep = (size_t)64 * Kfull;
    const size_t halfStep = (size_t)128 * Kfull;

    char* ldsA0 = (char*)&sA[0][0][0][0] + wid * 1024;
    char* ldsB0 = (char*)&sB[0][0][0][0] + wid * 1024;

    // read-side swizzled LDS byte addresses (32-bit, for asm ds_read)
    const unsigned baseA = (unsigned)(uintptr_t)&sA[0][0][0][0];
    const unsigned baseB = (unsigned)(uintptr_t)&sB[0][0][0][0];
    const unsigned g0 = (((lane >> 4)) ^ (lane & 7)) << 4;
    const unsigned g1 = ((4 + (lane >> 4)) ^ (lane & 7)) << 4;
    const unsigned rdA0 = baseA + wr * 16384 + (lane & 15) * 128 + g0;
    const unsigned rdA1 = baseA + wr * 16384 + (lane & 15) * 128 + g1;
    const unsigned rdB0 = baseB + (wc >> 1) * 16384 + (wc & 1) * 8192 + (lane & 15) * 128 + g0;
    const unsigned rdB1 = baseB + (wc >> 1) * 16384 + (wc & 1) * 8192 + (lane & 15) * 128 + g1;

    f32x4 acc[8][4] = {};
    bf16x8 aF[4][2], b01[2][2], b23[2][2];

#define STAGE_A(buf, half, t)                                              \
    do {                                                                   \
        const __hip_bfloat16* _g = gA + (half) * halfStep + (size_t)(t) * 64; \
        char* _l = ldsA0 + (buf) * 32768 + (half) * 16384;                 \
        gll16(_g, _l);                                                     \
        gll16(_g + rowStep, _l + 8192);                                    \
    } while (0)
#define STAGE_B(buf, half, t)                                              \
    do {                                                                   \
        const __hip_bfloat16* _g = gB + (half) * halfStep + (size_t)(t) * 64; \
        char* _l = ldsB0 + (buf) * 32768 + (half) * 16384;                 \
        gll16(_g, _l);                                                     \
        gll16(_g + rowStep, _l + 8192);                                    \
    } while (0)
#define PIN() __builtin_amdgcn_sched_barrier(0)
#define BAR()                              \
    do {                                   \
        PIN();                             \
        __builtin_amdgcn_s_barrier();      \
        PIN();                             \
    } while (0)
#define WAIT_LGKM0() __builtin_amdgcn_s_waitcnt(0xC07F)  // lgkmcnt(0)
#define WAIT_LGKM8() __builtin_amdgcn_s_waitcnt(0xC87F)  // lgkmcnt(8)
#define WAIT_VM4() __builtin_amdgcn_s_waitcnt(0x0F74)    // vmcnt(4)
#define WAIT_VM0() __builtin_amdgcn_s_waitcnt(0x0F70)    // vmcnt(0)
// fragment reads: asm ds_read_b128 at swizzled address
#define RDA(buf, r, ks) ds_read128(((ks) ? rdA1 : rdA0) + (buf) * 32768u + (r) * 2048u)
#define RDB(buf, r, ks) ds_read128(((ks) ? rdB1 : rdB0) + (buf) * 32768u + (r) * 2048u)
#define MM_Q(mbase, nbase, bfr)                                                   \
    _Pragma("unroll") for (int ks = 0; ks < 2; ++ks)                              \
    _Pragma("unroll") for (int m = 0; m < 4; ++m)                                 \
    _Pragma("unroll") for (int n = 0; n < 2; ++n)                                 \
        acc[(mbase) + m][(nbase) + n] = __builtin_amdgcn_mfma_f32_16x16x32_bf16(  \
            aF[m][ks], bfr[n][ks], acc[(mbase) + m][(nbase) + n], 0, 0, 0);
#define MFMA_PHASE(mbase, nbase, bfr)     \
    do {                                  \
        WAIT_LGKM0();                     \
        PIN();                            \
        __builtin_amdgcn_s_setprio(1);    \
        MM_Q(mbase, nbase, bfr);          \
        __builtin_amdgcn_s_setprio(0);    \
        PIN();                            \
    } while (0)

    // prologue: tile0 (all 4 halves, buf0) + tile1 B-halves (buf1).
    STAGE_B(0, 0, 0);
    STAGE_B(0, 1, 0);
    STAGE_A(0, 0, 0);
    STAGE_A(0, 1, 0);
    STAGE_B(1, 0, 1);
    STAGE_B(1, 1, 1);
    WAIT_VM4();
    BAR();

    const int iters = nt >> 1;
    for (int i = 0; i < iters; ++i) {
        const bool full = (i + 1 < iters);
        const int t1 = 2 * i + 1, t2 = 2 * i + 2, t3 = 2 * i + 3;

        // phase 1: tile 2i (buf0): read A[m0-3]+B[n0-1]; MFMA m0-3 x n0-1
#pragma unroll
        for (int m = 0; m < 4; ++m) {
            aF[m][0] = RDA(0, m, 0);
            aF[m][1] = RDA(0, m, 1);
        }
#pragma unroll
        for (int n = 0; n < 2; ++n) {
            b01[n][0] = RDB(0, n, 0);
            b01[n][1] = RDB(0, n, 1);
        }
        STAGE_A(1, 0, t1);
        WAIT_LGKM8();
        BAR();
        MFMA_PHASE(0, 0, b01);
        BAR();

        // phase 2: read B[n2-3]; MFMA m0-3 x n2-3
#pragma unroll
        for (int n = 0; n < 2; ++n) {
            b23[n][0] = RDB(0, 2 + n, 0);
            b23[n][1] = RDB(0, 2 + n, 1);
        }
        STAGE_A(1, 1, t1);
        BAR();
        MFMA_PHASE(0, 2, b23);
        BAR();

        // phase 3: read A[m4-7]; MFMA m4-7 x n2-3
#pragma unroll
        for (int m = 0; m < 4; ++m) {
            aF[m][0] = RDA(0, 4 + m, 0);
            aF[m][1] = RDA(0, 4 + m, 1);
        }
        if (full) STAGE_B(0, 0, t2);
        BAR();
        MFMA_PHASE(4, 2, b23);
        BAR();

        // phase 4: no ds_read; MFMA m4-7 x n0-1 (b01 kept in regs)
        if (full) STAGE_B(0, 1, t2);
        BAR();
        MFMA_PHASE(4, 0, b01);
        if (full)
            WAIT_VM4();
        else
            WAIT_VM0();
        BAR();

        // phase 5: tile 2i+1 (buf1): read A[m0-3]+B[n0-1]
#pragma unroll
        for (int m = 0; m < 4; ++m) {
            aF[m][0] = RDA(1, m, 0);
            aF[m][1] = RDA(1, m, 1);
        }
#pragma unroll
        for (int n = 0; n < 2; ++n) {
            b01[n][0] = RDB(1, n, 0);
            b01[n][1] = RDB(1, n, 1);
        }
        if (full) STAGE_A(0, 0, t2);
        WAIT_LGKM8();
        BAR();
        MFMA_PHASE(0, 0, b01);
        BAR();

        // phase 6: read B[n2-3]
#pragma unroll
        for (int n = 0; n < 2; ++n) {
            b23[n][0] = RDB(1, 2 + n, 0);
            b23[n][1] = RDB(1, 2 + n, 1);
        }
        if (full) STAGE_A(0, 1, t2);
        BAR();
        MFMA_PHASE(0, 2, b23);
        BAR();

        // phase 7: read A[m4-7]
#pragma unroll
        for (int m = 0; m < 4; ++m) {
            aF[m][0] = RDA(1, 4 + m, 0);
            aF[m][1] = RDA(1, 4 + m, 1);
        }
        if (full) STAGE_B(1, 0, t3);
        BAR();
        MFMA_PHASE(4, 2, b23);
        BAR();

        // phase 8: MFMA m4-7 x n0-1
        if (full) STAGE_B(1, 1, t3);
        BAR();
        MFMA_PHASE(4, 0, b01);
        if (full)
            WAIT_VM4();
        else
            WAIT_VM0();
        BAR();
    }

    // epilogue
    const int orow = brow + wr * 128 + ((lane >> 4) << 2);
    const int ocol = bcol + wc * 64 + (lane & 15);
#pragma unroll
    for (int m = 0; m < 8; ++m) {
#pragma unroll
        for (int j = 0; j < 4; ++j) {
            const int r = orow + m * 16 + j;
            const size_t ro = (size_t)r * Nout;
            if (EPI == 0) {
#pragma unroll
                for (int n = 0; n < 4; ++n) {
                    float v = acc[m][n][j];
                    float u = 1.5957691216057308f * (v + 0.044715f * v * v * v);
                    float g = v / (1.0f + __expf(-u));
                    hOut[ro + ocol + n * 16] = __float2bfloat16(g);
                }
            } else {
                const float sc = s[r];
#pragma unroll
                for (int n = 0; n < 4; ++n)
                    unsafeAtomicAdd(&fOut[ro + ocol + n * 16], sc * acc[m][n][j]);
            }
        }
    }
#undef STAGE_A
#undef STAGE_B
#undef PIN
#undef BAR
#undef WAIT_LGKM0
#undef WAIT_LGKM8
#undef WAIT_VM4
#undef WAIT_VM0
#undef RDA
#undef RDB
#undef MM_Q
#undef MFMA_PHASE
}

extern "C" void kernel_launch(void* const* d_in, const int* in_sizes, int n_in,
                              void* d_out, int out_size, void* d_ws, size_t ws_size,
                              hipStream_t stream) {
    const float* x = (const float*)d_in[0];
    // d_in[1] = scores (unused), d_in[3] = top_experts (unused)
    const float* ew = (const float*)d_in[2];
    const float* w1 = (const float*)d_in[4];
    const float* w2 = (const float*)d_in[5];
    float* out = (float*)d_out;

    char* ws = (char*)d_ws;
    float* s = (float*)ws;                                                    // 16 KB
    __hip_bfloat16* xb = (__hip_bfloat16*)(ws + 16384);                       // 8 MB
    __hip_bfloat16* w1t = (__hip_bfloat16*)(ws + 16384 + 8388608);            // 16 MB
    __hip_bfloat16* w2t = (__hip_bfloat16*)(ws + 16384 + 8388608 + 16777216); // 16 MB
    __hip_bfloat16* h = (__hip_bfloat16*)(ws + 16384 + 8388608 + 2 * 16777216); // 64 MB

    k_prep<<<1024, 256, 0, stream>>>(x, ew, xb, s, (TT * HID) / 4, TT);

    dim3 t1(INTER / 32, HID / 32);
    k_tcast<<<t1, 256, 0, stream>>>(w1, w1t, HID, INTER);
    dim3 t2(HID / 32, INTER / 32);
    k_tcast<<<t2, 256, 0, stream>>>(w2, w2t, INTER, HID);

    // GEMM1: [4096 x 1024] x [1024 x 8192] -> h (gelu, bf16)
    dim3 g1(INTER / 256, TT / 256, 1);  // 32 x 16
    k_gemm8<0><<<g1, 512, 0, stream>>>(xb, w1t, h, nullptr, nullptr, HID, HID / 64, INTER);

    // GEMM2: [4096 x 8192] x [8192 x 1024] -> out (f32, split-K=4 atomic combine)
    hipMemsetAsync(out, 0, (size_t)TT * HID * sizeof(float), stream);
    dim3 g2(HID / 256, TT / 256, 4);  // 4 x 16 x 4 = 256 blocks
    k_gemm8<1><<<g2, 512, 0, stream>>>(h, w2t, nullptr, out, s, INTER, 2048 / 64, HID);
}